// Round 9
// baseline (751.082 us; speedup 1.0000x reference)
//
#include <hip/hip_runtime.h>
#include <hip/hip_bf16.h>

#define D 128
#define BSH 6                 // bucket = row >> 6 (64 rows/bucket)
#define BROWS 64
#define AP 136                // padded bf16 row for A tiles (272B stride)

typedef __attribute__((ext_vector_type(8))) short bf16x8;
typedef __attribute__((ext_vector_type(8))) unsigned short ushort8;
typedef __attribute__((ext_vector_type(4))) float f32x4;

static __device__ __forceinline__ unsigned short f2bf(float f) {
    unsigned int u = __builtin_bit_cast(unsigned int, f);
    unsigned int r = (u + 0x7FFFu + ((u >> 16) & 1u)) >> 16;
    return (unsigned short)r;
}
static __device__ __forceinline__ float bf2f(unsigned short u) {
    return __builtin_bit_cast(float, ((unsigned int)u) << 16);
}

// ---- setup: x->bf16, Wcat, zero BN acc, per-block bucket histograms -------
// ghT layout: [bucket][block-slot], slot stride 128 (eblocks <= 128)
__global__ __launch_bounds__(256) void setup_k(const float* __restrict__ x,
                                               const float* __restrict__ Wl,
                                               const float* __restrict__ Wr,
                                               const int* __restrict__ rowi,
                                               unsigned short* __restrict__ xbf,
                                               unsigned short* __restrict__ Wcat,
                                               int* __restrict__ ghT,
                                               float* __restrict__ bn_acc,
                                               int N, int NB, int E, int eblocks) {
    __shared__ int hist[1024];
    int t = threadIdx.x;
    int gid = blockIdx.x * 256 + t;
    int stride = gridDim.x * 256;
    int total4 = N * D / 4;
    for (int i = gid; i < total4; i += stride) {
        float4 v = reinterpret_cast<const float4*>(x)[i];
        ushort4 o;
        o.x = f2bf(v.x); o.y = f2bf(v.y); o.z = f2bf(v.z); o.w = f2bf(v.w);
        reinterpret_cast<ushort4*>(xbf)[i] = o;
    }
    for (int i = gid; i < D * 2 * D; i += stride) {
        int o = i >> 8, k = i & 255;
        float v = (k < D) ? Wl[o * D + k] : Wr[o * D + (k - D)];
        Wcat[i] = f2bf(v);
    }
    if (gid < 2 * D) bn_acc[gid] = 0.f;

    if (blockIdx.x < (unsigned)eblocks) {
        for (int i = t; i < NB; i += 256) hist[i] = 0;
        __syncthreads();
        int base = blockIdx.x * 8192;
        #pragma unroll
        for (int k = 0; k < 32; ++k) {
            int e = base + k * 256 + t;
            if (e < E) atomicAdd(&hist[rowi[e] >> BSH], 1);
        }
        __syncthreads();
        for (int i = t; i < NB; i += 256) ghT[i * 128 + blockIdx.x] = hist[i];
    }
}

// ---- scanB: sum transposed slices + exclusive scan (NB <= 1024) -----------
__global__ __launch_bounds__(1024) void scanB_k(const int* __restrict__ ghT,
                                                int* __restrict__ bstart,
                                                int* __restrict__ gcur,
                                                int NB, int E, int eb) {
    __shared__ int lds[1024];
    int t = threadIdx.x;
    int v = 0;
    if (t < NB) {
        const int* row = ghT + (size_t)t * 128;
        int b = 0;
        for (; b + 4 <= eb; b += 4) {
            int4 q = *reinterpret_cast<const int4*>(row + b);
            v += q.x + q.y + q.z + q.w;
        }
        for (; b < eb; ++b) v += row[b];
    }
    lds[t] = v;
    __syncthreads();
    #pragma unroll
    for (int off = 1; off < 1024; off <<= 1) {
        int u = (t >= off) ? lds[t - off] : 0;
        __syncthreads();
        lds[t] += u;
        __syncthreads();
    }
    if (t < NB) {
        int s = lds[t] - v;
        bstart[t] = s;
        gcur[t] = s;
    }
    if (t == 0) bstart[NB] = E;
}

// ---- binB: scatter edges into bucket regions, packed (row<<16)|col --------
__global__ __launch_bounds__(256) void binB_k(const int* __restrict__ rowi,
                                              const int* __restrict__ coli,
                                              int* __restrict__ gcur,
                                              unsigned int* __restrict__ binned,
                                              int E, int NB) {
    __shared__ unsigned int stage[8192];
    __shared__ int hist[1024];
    __shared__ int basep[1024];
    __shared__ int cur[1024];
    int t = threadIdx.x;
    for (int i = t; i < NB; i += 256) { hist[i] = 0; cur[i] = 0; }
    __syncthreads();
    int base = blockIdx.x * 8192;
    int cnt = E - base; if (cnt > 8192) cnt = 8192;
    #pragma unroll
    for (int k = 0; k < 32; ++k) {
        int i = k * 256 + t;
        if (i < cnt) {
            int r = rowi[base + i], c = coli[base + i];
            stage[i] = ((unsigned int)r << 16) | (unsigned int)c;
            atomicAdd(&hist[r >> BSH], 1);
        }
    }
    __syncthreads();
    for (int i = t; i < NB; i += 256) {
        int h = hist[i];
        basep[i] = h ? atomicAdd(&gcur[i], h) : 0;
    }
    __syncthreads();
    #pragma unroll
    for (int k = 0; k < 32; ++k) {
        int i = k * 256 + t;
        if (i < cnt) {
            unsigned int p = stage[i];
            int b = p >> (16 + BSH);
            int pos = basep[b] + atomicAdd(&cur[b], 1);
            binned[pos] = p;
        }
    }
}

// ---- aggemm: edge-parallel gather + LDS f32 atomic accum + MFMA + BN ------
// block b owns nodes [b*64, b*64+64); 512 thr = 8 waves
// edge phase: waves stream contiguous slices of the bucket's binned range,
//   16 gathers in flight, ds_add_f32 into accf[row][col]
// gemm phase: wave w computes output cols [w*16, w*16+16) for all 64 rows
__global__ __launch_bounds__(512) void aggemm_k(const unsigned short* __restrict__ xbf,
                                                const unsigned int* __restrict__ binned,
                                                const int* __restrict__ bstart,
                                                const unsigned short* __restrict__ Wcat,
                                                const float* __restrict__ bl,
                                                const float* __restrict__ br,
                                                unsigned short* __restrict__ hbf,
                                                float* __restrict__ bn_sum,
                                                float* __restrict__ bn_ss, int N) {
    __shared__ unsigned short A_x[BROWS][AP];           // 17408 B
    __shared__ __align__(16) float accf[BROWS][D];      // 32768 B (A_agg aliases)
    __shared__ float bn_lds[2 * D];
    unsigned short (*A_agg)[AP] = reinterpret_cast<unsigned short (*)[AP]>(&accf[0][0]);

    int t = threadIdx.x;
    int b = blockIdx.x;
    int w = __builtin_amdgcn_readfirstlane(t >> 6);
    int lane = t & 63;
    int lr = lane & 15, lk = lane >> 4;

    if (t < 2 * D) bn_lds[t] = 0.f;

    // zero accf: 16 floats (4 x float4) per thread
    {
        float4 z = make_float4(0.f, 0.f, 0.f, 0.f);
        float4* dst = reinterpret_cast<float4*>(&accf[0][0]) + t * 4;
        dst[0] = z; dst[1] = z; dst[2] = z; dst[3] = z;
    }
    // stage own-row x -> A_x (loads retire under the edge stream)
    #pragma unroll
    for (int k = 0; k < 2; ++k) {
        int ch = k * 512 + t;
        int r = ch >> 4, c16 = ch & 15;
        int node = b * BROWS + r;
        ushort8 v = (ushort8){0, 0, 0, 0, 0, 0, 0, 0};
        if (node < N) v = *reinterpret_cast<const ushort8*>(&xbf[(size_t)node * D + c16 * 8]);
        *reinterpret_cast<ushort8*>(&A_x[r][c16 * 8]) = v;
    }
    __syncthreads();   // accf zeroed before any atomics

    // ---------- edge-parallel gather ----------
    int s = bstart[b], e = bstart[b + 1];
    int total = e - s;
    int per = (total + 7) >> 3;
    int js = s + w * per;
    int je = js + per; if (je > e) je = e;
    const unsigned short* xb = xbf + lane * 2;

    int j = js;
    for (; j + 16 <= je; j += 16) {
        unsigned int p[16];
        #pragma unroll
        for (int q = 0; q < 16; ++q) p[q] = binned[j + q];
        unsigned int v[16];
        #pragma unroll
        for (int q = 0; q < 16; ++q)
            v[q] = *reinterpret_cast<const unsigned int*>(
                xb + (size_t)(p[q] & 0xFFFFu) * D);
        #pragma unroll
        for (int q = 0; q < 16; ++q) {
            int r = (p[q] >> 16) & (BROWS - 1);
            atomicAdd(&accf[r][lane * 2],     bf2f((unsigned short)v[q]));
            atomicAdd(&accf[r][lane * 2 + 1], bf2f((unsigned short)(v[q] >> 16)));
        }
    }
    if (j + 8 <= je) {
        unsigned int p[8];
        #pragma unroll
        for (int q = 0; q < 8; ++q) p[q] = binned[j + q];
        unsigned int v[8];
        #pragma unroll
        for (int q = 0; q < 8; ++q)
            v[q] = *reinterpret_cast<const unsigned int*>(
                xb + (size_t)(p[q] & 0xFFFFu) * D);
        #pragma unroll
        for (int q = 0; q < 8; ++q) {
            int r = (p[q] >> 16) & (BROWS - 1);
            atomicAdd(&accf[r][lane * 2],     bf2f((unsigned short)v[q]));
            atomicAdd(&accf[r][lane * 2 + 1], bf2f((unsigned short)(v[q] >> 16)));
        }
        j += 8;
    }
    for (; j < je; ++j) {
        unsigned int p = binned[j];
        unsigned int v = *reinterpret_cast<const unsigned int*>(
            xb + (size_t)(p & 0xFFFFu) * D);
        int r = (p >> 16) & (BROWS - 1);
        atomicAdd(&accf[r][lane * 2],     bf2f((unsigned short)v));
        atomicAdd(&accf[r][lane * 2 + 1], bf2f((unsigned short)(v >> 16)));
    }
    __syncthreads();   // all atomics done

    // ---------- in-place convert accf (f32) -> A_agg (bf16, padded) --------
    {
        int r = t >> 3;
        int c0 = (t & 7) * 16;
        float vv[16];
        #pragma unroll
        for (int q = 0; q < 4; ++q) {
            float4 f = *reinterpret_cast<const float4*>(&accf[r][c0 + q * 4]);
            vv[q * 4 + 0] = f.x; vv[q * 4 + 1] = f.y;
            vv[q * 4 + 2] = f.z; vv[q * 4 + 3] = f.w;
        }
        __syncthreads();   // all reads done before overwriting
        #pragma unroll
        for (int q = 0; q < 8; ++q) {
            unsigned int ow = (unsigned int)f2bf(vv[2 * q])
                            | ((unsigned int)f2bf(vv[2 * q + 1]) << 16);
            *reinterpret_cast<unsigned int*>(&A_agg[r][c0 + 2 * q]) = ow;
        }
    }
    // B fragments: wave w cols [w*16, w*16+16)
    bf16x8 Breg[8];
    #pragma unroll
    for (int ks = 0; ks < 8; ++ks)
        Breg[ks] = *reinterpret_cast<const bf16x8*>(
            &Wcat[(w * 16 + lr) * 256 + ks * 32 + lk * 8]);
    __syncthreads();

    // ---------- MFMA: K=256 (agg half + x half) ----------
    f32x4 acc[4];
    #pragma unroll
    for (int m = 0; m < 4; ++m) acc[m] = (f32x4){0.f, 0.f, 0.f, 0.f};
    #pragma unroll
    for (int m = 0; m < 4; ++m) {
        #pragma unroll
        for (int ks = 0; ks < 4; ++ks) {
            bf16x8 a = *reinterpret_cast<const bf16x8*>(&A_agg[m * 16 + lr][ks * 32 + lk * 8]);
            acc[m] = __builtin_amdgcn_mfma_f32_16x16x32_bf16(a, Breg[ks], acc[m], 0, 0, 0);
        }
        #pragma unroll
        for (int ks = 0; ks < 4; ++ks) {
            bf16x8 a = *reinterpret_cast<const bf16x8*>(&A_x[m * 16 + lr][ks * 32 + lk * 8]);
            acc[m] = __builtin_amdgcn_mfma_f32_16x16x32_bf16(a, Breg[ks + 4], acc[m], 0, 0, 0);
        }
    }

    // ---------- epilogue: bias + relu + store bf16 h + BN partials ----------
    int colo = w * 16 + lr;
    float bias = bl[colo] + br[colo];
    float s1 = 0.f, s2 = 0.f;
    #pragma unroll
    for (int m = 0; m < 4; ++m)
        #pragma unroll
        for (int ee = 0; ee < 4; ++ee) {
            int node = b * BROWS + m * 16 + lk * 4 + ee;
            if (node < N) {
                float hv = acc[m][ee] + bias;
                hv = hv > 0.f ? hv : 0.f;
                hbf[(size_t)node * D + colo] = f2bf(hv);
                s1 += hv;
                s2 += hv * hv;
            }
        }
    atomicAdd(&bn_lds[colo], s1);
    atomicAdd(&bn_lds[D + colo], s2);
    __syncthreads();
    if (t < D) {
        atomicAdd(&bn_sum[t], bn_lds[t]);
        atomicAdd(&bn_ss[t], bn_lds[D + t]);
    }
}

// ---- bnapply: out = h*scale + shift (finalize folded in) ------------------
__global__ __launch_bounds__(256) void bnapply_k(const unsigned short* __restrict__ hbf,
                                                 float* __restrict__ out,
                                                 const float* __restrict__ bn_sum,
                                                 const float* __restrict__ bn_ss,
                                                 const float* __restrict__ gamma,
                                                 const float* __restrict__ beta,
                                                 int total8, float invN) {
    int gid = blockIdx.x * 256 + threadIdx.x;
    if (gid >= total8) return;
    int d8 = (gid & 15) * 8;
    ushort8 hv = *reinterpret_cast<const ushort8*>(&hbf[(size_t)gid * 8]);
    float4 o0, o1;
    #pragma unroll
    for (int q = 0; q < 8; ++q) {
        int d = d8 + q;
        float m = bn_sum[d] * invN;
        float var = bn_ss[d] * invN - m * m;
        float r = rsqrtf(var + 1e-5f);
        float sc = gamma[d] * r;
        float sh = beta[d] - m * sc;
        float o = bf2f((unsigned short)hv[q]) * sc + sh;
        if (q < 4) { (&o0.x)[q] = o; } else { (&o1.x)[q - 4] = o; }
    }
    *reinterpret_cast<float4*>(out + (size_t)gid * 8) = o0;
    *reinterpret_cast<float4*>(out + (size_t)gid * 8 + 4) = o1;
}

extern "C" void kernel_launch(void* const* d_in, const int* in_sizes, int n_in,
                              void* d_out, int out_size, void* d_ws, size_t ws_size,
                              hipStream_t stream) {
    const float* x     = (const float*)d_in[0];
    const int*   ei    = (const int*)d_in[1];
    const float* Wl    = (const float*)d_in[2];
    const float* bl    = (const float*)d_in[3];
    const float* Wr    = (const float*)d_in[4];
    const float* br    = (const float*)d_in[5];
    const float* gamma = (const float*)d_in[6];
    const float* beta  = (const float*)d_in[7];
    int N = in_sizes[0] / D;
    int E = in_sizes[1] / 2;
    int NB = (N + BROWS - 1) / BROWS;    // 782 (must be <= 1024)
    int eblocks = (E + 8191) / 8192;     // 98 (must be <= 128)

    float* ws = (float*)d_ws;
    float* bn_sum = ws;                                   // D
    float* bn_ss  = ws + D;                               // D
    unsigned short* xbf  = (unsigned short*)(ws + 4 * D); // N*D
    unsigned short* hbf  = xbf + (size_t)N * D;           // N*D
    unsigned short* Wcat = hbf + (size_t)N * D;           // 2*D*D
    int* gcur   = (int*)(Wcat + 2 * D * D);               // pad 1024
    int* bstart = gcur + 1024;                            // pad 1028
    int* ghT    = bstart + 1028;                          // 1024*128
    unsigned int* binned = (unsigned int*)(ghT + 1024 * 128); // E
    float* out = (float*)d_out;

    const int* rowi = ei;
    const int* coli = ei + E;

    setup_k<<<2048, 256, 0, stream>>>(x, Wl, Wr, rowi, xbf, Wcat, ghT, bn_sum,
                                      N, NB, E, eblocks);
    scanB_k<<<1, 1024, 0, stream>>>(ghT, bstart, gcur, NB, E, eblocks);
    binB_k<<<eblocks, 256, 0, stream>>>(rowi, coli, gcur, binned, E, NB);
    aggemm_k<<<NB, 512, 0, stream>>>(xbf, binned, bstart, Wcat, bl, br,
                                     hbf, bn_sum, bn_ss, N);
    int total8 = N * D / 8;
    bnapply_k<<<(total8 + 255) / 256, 256, 0, stream>>>(hbf, out, bn_sum, bn_ss,
                                                        gamma, beta, total8,
                                                        1.0f / (float)N);
}

// Round 10
// 135.367 us; speedup vs baseline: 5.5485x; 5.5485x over previous
//
#include <hip/hip_runtime.h>
#include <hip/hip_bf16.h>

#define D 128
#define BSH 6                 // bucket = row >> 6 (64 rows/bucket) for binning
#define BROWS 64
#define HR 32                 // rows per aggemm block (half bucket)
#define CH 2048               // edges scanned per chunk in aggemm
#define AP 136                // padded bf16 row for A tiles (272B stride)

typedef __attribute__((ext_vector_type(8))) short bf16x8;
typedef __attribute__((ext_vector_type(8))) unsigned short ushort8;
typedef __attribute__((ext_vector_type(4))) float f32x4;

static __device__ __forceinline__ unsigned short f2bf(float f) {
    unsigned int u = __builtin_bit_cast(unsigned int, f);
    unsigned int r = (u + 0x7FFFu + ((u >> 16) & 1u)) >> 16;
    return (unsigned short)r;
}
static __device__ __forceinline__ float bf2f(unsigned short u) {
    return __builtin_bit_cast(float, ((unsigned int)u) << 16);
}

// ---- setup: x->bf16, Wcat, zero BN acc, per-block bucket histograms -------
// ghT layout: [bucket][block-slot], slot stride 128 (eblocks <= 128)
__global__ __launch_bounds__(256) void setup_k(const float* __restrict__ x,
                                               const float* __restrict__ Wl,
                                               const float* __restrict__ Wr,
                                               const int* __restrict__ rowi,
                                               unsigned short* __restrict__ xbf,
                                               unsigned short* __restrict__ Wcat,
                                               int* __restrict__ ghT,
                                               float* __restrict__ bn_acc,
                                               int N, int NB, int E, int eblocks) {
    __shared__ int hist[1024];
    int t = threadIdx.x;
    int gid = blockIdx.x * 256 + t;
    int stride = gridDim.x * 256;
    int total4 = N * D / 4;
    for (int i = gid; i < total4; i += stride) {
        float4 v = reinterpret_cast<const float4*>(x)[i];
        ushort4 o;
        o.x = f2bf(v.x); o.y = f2bf(v.y); o.z = f2bf(v.z); o.w = f2bf(v.w);
        reinterpret_cast<ushort4*>(xbf)[i] = o;
    }
    for (int i = gid; i < D * 2 * D; i += stride) {
        int o = i >> 8, k = i & 255;
        float v = (k < D) ? Wl[o * D + k] : Wr[o * D + (k - D)];
        Wcat[i] = f2bf(v);
    }
    if (gid < 2 * D) bn_acc[gid] = 0.f;

    if (blockIdx.x < (unsigned)eblocks) {
        for (int i = t; i < NB; i += 256) hist[i] = 0;
        __syncthreads();
        int base = blockIdx.x * 8192;
        #pragma unroll
        for (int k = 0; k < 32; ++k) {
            int e = base + k * 256 + t;
            if (e < E) atomicAdd(&hist[rowi[e] >> BSH], 1);
        }
        __syncthreads();
        for (int i = t; i < NB; i += 256) ghT[i * 128 + blockIdx.x] = hist[i];
    }
}

// ---- scanB: sum transposed slices + exclusive scan (NB <= 1024) -----------
__global__ __launch_bounds__(1024) void scanB_k(const int* __restrict__ ghT,
                                                int* __restrict__ bstart,
                                                int* __restrict__ gcur,
                                                int NB, int E, int eb) {
    __shared__ int lds[1024];
    int t = threadIdx.x;
    int v = 0;
    if (t < NB) {
        const int* row = ghT + (size_t)t * 128;
        int b = 0;
        for (; b + 4 <= eb; b += 4) {
            int4 q = *reinterpret_cast<const int4*>(row + b);
            v += q.x + q.y + q.z + q.w;
        }
        for (; b < eb; ++b) v += row[b];
    }
    lds[t] = v;
    __syncthreads();
    #pragma unroll
    for (int off = 1; off < 1024; off <<= 1) {
        int u = (t >= off) ? lds[t - off] : 0;
        __syncthreads();
        lds[t] += u;
        __syncthreads();
    }
    if (t < NB) {
        int s = lds[t] - v;
        bstart[t] = s;
        gcur[t] = s;
    }
    if (t == 0) bstart[NB] = E;
}

// ---- binB: scatter edges into bucket regions, packed (row<<16)|col --------
__global__ __launch_bounds__(256) void binB_k(const int* __restrict__ rowi,
                                              const int* __restrict__ coli,
                                              int* __restrict__ gcur,
                                              unsigned int* __restrict__ binned,
                                              int E, int NB) {
    __shared__ unsigned int stage[8192];
    __shared__ int hist[1024];
    __shared__ int basep[1024];
    __shared__ int cur[1024];
    int t = threadIdx.x;
    for (int i = t; i < NB; i += 256) { hist[i] = 0; cur[i] = 0; }
    __syncthreads();
    int base = blockIdx.x * 8192;
    int cnt = E - base; if (cnt > 8192) cnt = 8192;
    #pragma unroll
    for (int k = 0; k < 32; ++k) {
        int i = k * 256 + t;
        if (i < cnt) {
            int r = rowi[base + i], c = coli[base + i];
            stage[i] = ((unsigned int)r << 16) | (unsigned int)c;
            atomicAdd(&hist[r >> BSH], 1);
        }
    }
    __syncthreads();
    for (int i = t; i < NB; i += 256) {
        int h = hist[i];
        basep[i] = h ? atomicAdd(&gcur[i], h) : 0;
    }
    __syncthreads();
    #pragma unroll
    for (int k = 0; k < 32; ++k) {
        int i = k * 256 + t;
        if (i < cnt) {
            unsigned int p = stage[i];
            int b = p >> (16 + BSH);
            int pos = basep[b] + atomicAdd(&cur[b], 1);
            binned[pos] = p;
        }
    }
}

// ---- aggemm: half-bucket sort + register agg + MFMA GEMM + BN -------------
// block handles rows [bk*64 + half*32, +32), bk = blockIdx>>1, half = blockIdx&1
// 256 thr = 4 waves; agg: wave w owns rows [w*8, w*8+8); gemm: wave w owns
// output cols [w*32, w*32+32) for all 32 rows.
__global__ __launch_bounds__(256) void aggemm_k(const unsigned short* __restrict__ xbf,
                                                const unsigned int* __restrict__ binned,
                                                const int* __restrict__ bstart,
                                                const unsigned short* __restrict__ Wcat,
                                                const float* __restrict__ bl,
                                                const float* __restrict__ br,
                                                unsigned short* __restrict__ hbf,
                                                float* __restrict__ bn_sum,
                                                float* __restrict__ bn_ss, int N) {
    __shared__ unsigned short A_x[HR][AP];                     // 8704 B
    __shared__ __align__(16) unsigned char ubuf[HR * AP * 2];  // sorted / A_agg union
    __shared__ int hist[HR];
    __shared__ int sincl[HR];
    __shared__ int sstart[HR + 1];
    __shared__ int scur[HR];
    __shared__ float bn_lds[2 * D];

    unsigned int* sorted = reinterpret_cast<unsigned int*>(ubuf);   // CH*4 = 8192 <= 8704
    unsigned short (*A_agg)[AP] = reinterpret_cast<unsigned short (*)[AP]>(ubuf);

    int t = threadIdx.x;
    int bk = blockIdx.x >> 1;
    int half = blockIdx.x & 1;
    int nodeBase = bk * BROWS + half * HR;
    int s = bstart[bk], e = bstart[bk + 1];
    int w = t >> 6, lane = t & 63;
    int lr = lane & 15, lk = lane >> 4;

    bn_lds[t] = 0.f;   // 256 = 2*D

    // stage own-row x -> A_x (loads retire under the sort/agg phase)
    #pragma unroll
    for (int k = 0; k < 2; ++k) {
        int ch = k * 256 + t;          // 0..511
        int r = ch >> 4;               // 0..31
        int c16 = ch & 15;             // 16B chunk
        int node = nodeBase + r;
        ushort8 v = (ushort8){0, 0, 0, 0, 0, 0, 0, 0};
        if (node < N) v = *reinterpret_cast<const ushort8*>(&xbf[(size_t)node * D + c16 * 8]);
        *reinterpret_cast<ushort8*>(&A_x[r][c16 * 8]) = v;
    }

    // ---------- agg phase (counting sort of own-half edges per chunk) ------
    float a0[8], a1[8];
    #pragma unroll
    for (int i = 0; i < 8; ++i) { a0[i] = 0.f; a1[i] = 0.f; }
    const unsigned short* xb = xbf + lane * 2;

    for (int cs = s; cs < e; cs += CH) {
        int cnt = e - cs; if (cnt > CH) cnt = CH;
        if (t < HR) hist[t] = 0;
        __syncthreads();
        // count own-half edges by row-in-half
        #pragma unroll
        for (int k = 0; k < CH / 256; ++k) {
            int i = k * 256 + t;
            if (i < cnt) {
                unsigned int p = binned[cs + i];
                int rowin = (p >> 16) & (BROWS - 1);
                if ((rowin >> 5) == half) atomicAdd(&hist[rowin & (HR - 1)], 1);
            }
        }
        __syncthreads();
        if (t < HR) sincl[t] = hist[t];
        __syncthreads();
        #pragma unroll
        for (int off = 1; off < HR; off <<= 1) {
            int u = 0;
            if (t < HR && t >= off) u = sincl[t - off];
            __syncthreads();
            if (t < HR) sincl[t] += u;
            __syncthreads();
        }
        if (t < HR) {
            int ex = sincl[t] - hist[t];
            sstart[t] = ex;
            scur[t] = ex;
        }
        if (t == HR - 1) sstart[HR] = sincl[HR - 1];
        __syncthreads();
        // scatter own-half edges into row-sorted order
        #pragma unroll
        for (int k = 0; k < CH / 256; ++k) {
            int i = k * 256 + t;
            if (i < cnt) {
                unsigned int p = binned[cs + i];
                int rowin = (p >> 16) & (BROWS - 1);
                if ((rowin >> 5) == half) {
                    int pos = atomicAdd(&scur[rowin & (HR - 1)], 1);
                    sorted[pos] = p;
                }
            }
        }
        __syncthreads();
        // aggregate: wave w owns rows [w*8, w*8+8), unroll-8 single stream
        #pragma unroll
        for (int i = 0; i < 8; ++i) {
            int r = w * 8 + i;
            int js = sstart[r], je = sstart[r + 1];
            float s0 = a0[i], s1 = a1[i];
            int j = js;
            for (; j + 8 <= je; j += 8) {
                unsigned int v[8];
                #pragma unroll
                for (int q = 0; q < 8; ++q)
                    v[q] = *reinterpret_cast<const unsigned int*>(
                        xb + (size_t)(sorted[j + q] & 0xFFFFu) * D);
                #pragma unroll
                for (int q = 0; q < 8; ++q) {
                    s0 += bf2f((unsigned short)v[q]);
                    s1 += bf2f((unsigned short)(v[q] >> 16));
                }
            }
            if (j + 4 <= je) {
                unsigned int v[4];
                #pragma unroll
                for (int q = 0; q < 4; ++q)
                    v[q] = *reinterpret_cast<const unsigned int*>(
                        xb + (size_t)(sorted[j + q] & 0xFFFFu) * D);
                #pragma unroll
                for (int q = 0; q < 4; ++q) {
                    s0 += bf2f((unsigned short)v[q]);
                    s1 += bf2f((unsigned short)(v[q] >> 16));
                }
                j += 4;
            }
            for (; j < je; ++j) {
                unsigned int v = *reinterpret_cast<const unsigned int*>(
                    xb + (size_t)(sorted[j] & 0xFFFFu) * D);
                s0 += bf2f((unsigned short)v);
                s1 += bf2f((unsigned short)(v >> 16));
            }
            a0[i] = s0; a1[i] = s1;
        }
        __syncthreads();   // all waves done reading sorted for this chunk
    }

    // ---------- write agg -> A_agg (union buf), hoist B ----------
    #pragma unroll
    for (int i = 0; i < 8; ++i) {
        int r = w * 8 + i;
        unsigned int o = (unsigned int)f2bf(a0[i]) | ((unsigned int)f2bf(a1[i]) << 16);
        *reinterpret_cast<unsigned int*>(&A_agg[r][lane * 2]) = o;
    }
    // B fragments: wave w cols [w*32, w*32+32)
    bf16x8 Breg[2][8];
    #pragma unroll
    for (int g2 = 0; g2 < 2; ++g2)
        #pragma unroll
        for (int ks = 0; ks < 8; ++ks)
            Breg[g2][ks] = *reinterpret_cast<const bf16x8*>(
                &Wcat[((w * 2 + g2) * 16 + lr) * 256 + ks * 32 + lk * 8]);
    __syncthreads();

    // ---------- MFMA: K=256 (agg half + x half), 32 rows ----------
    f32x4 acc[2][2];
    #pragma unroll
    for (int m = 0; m < 2; ++m)
        #pragma unroll
        for (int g2 = 0; g2 < 2; ++g2) acc[m][g2] = (f32x4){0.f, 0.f, 0.f, 0.f};
    #pragma unroll
    for (int m = 0; m < 2; ++m) {
        #pragma unroll
        for (int ks = 0; ks < 4; ++ks) {
            bf16x8 a = *reinterpret_cast<const bf16x8*>(&A_agg[m * 16 + lr][ks * 32 + lk * 8]);
            acc[m][0] = __builtin_amdgcn_mfma_f32_16x16x32_bf16(a, Breg[0][ks], acc[m][0], 0, 0, 0);
            acc[m][1] = __builtin_amdgcn_mfma_f32_16x16x32_bf16(a, Breg[1][ks], acc[m][1], 0, 0, 0);
        }
        #pragma unroll
        for (int ks = 0; ks < 4; ++ks) {
            bf16x8 a = *reinterpret_cast<const bf16x8*>(&A_x[m * 16 + lr][ks * 32 + lk * 8]);
            acc[m][0] = __builtin_amdgcn_mfma_f32_16x16x32_bf16(a, Breg[0][ks + 4], acc[m][0], 0, 0, 0);
            acc[m][1] = __builtin_amdgcn_mfma_f32_16x16x32_bf16(a, Breg[1][ks + 4], acc[m][1], 0, 0, 0);
        }
    }

    // ---------- epilogue: bias + relu + store bf16 h + BN partials ----------
    #pragma unroll
    for (int g2 = 0; g2 < 2; ++g2) {
        int colo = w * 32 + g2 * 16 + lr;
        float bias = bl[colo] + br[colo];
        float s1 = 0.f, s2 = 0.f;
        #pragma unroll
        for (int m = 0; m < 2; ++m)
            #pragma unroll
            for (int ee = 0; ee < 4; ++ee) {
                int node = nodeBase + m * 16 + lk * 4 + ee;
                if (node < N) {
                    float hv = acc[m][g2][ee] + bias;
                    hv = hv > 0.f ? hv : 0.f;
                    hbf[(size_t)node * D + colo] = f2bf(hv);
                    s1 += hv;
                    s2 += hv * hv;
                }
            }
        atomicAdd(&bn_lds[colo], s1);
        atomicAdd(&bn_lds[D + colo], s2);
    }
    __syncthreads();
    if (t < D) {
        atomicAdd(&bn_sum[t], bn_lds[t]);
        atomicAdd(&bn_ss[t], bn_lds[D + t]);
    }
}

// ---- bnapply: out = h*scale + shift (finalize folded in) ------------------
__global__ __launch_bounds__(256) void bnapply_k(const unsigned short* __restrict__ hbf,
                                                 float* __restrict__ out,
                                                 const float* __restrict__ bn_sum,
                                                 const float* __restrict__ bn_ss,
                                                 const float* __restrict__ gamma,
                                                 const float* __restrict__ beta,
                                                 int total8, float invN) {
    int gid = blockIdx.x * 256 + threadIdx.x;
    if (gid >= total8) return;
    int d8 = (gid & 15) * 8;
    ushort8 hv = *reinterpret_cast<const ushort8*>(&hbf[(size_t)gid * 8]);
    float4 o0, o1;
    #pragma unroll
    for (int q = 0; q < 8; ++q) {
        int d = d8 + q;
        float m = bn_sum[d] * invN;
        float var = bn_ss[d] * invN - m * m;
        float r = rsqrtf(var + 1e-5f);
        float sc = gamma[d] * r;
        float sh = beta[d] - m * sc;
        float o = bf2f((unsigned short)hv[q]) * sc + sh;
        if (q < 4) { (&o0.x)[q] = o; } else { (&o1.x)[q - 4] = o; }
    }
    *reinterpret_cast<float4*>(out + (size_t)gid * 8) = o0;
    *reinterpret_cast<float4*>(out + (size_t)gid * 8 + 4) = o1;
}

extern "C" void kernel_launch(void* const* d_in, const int* in_sizes, int n_in,
                              void* d_out, int out_size, void* d_ws, size_t ws_size,
                              hipStream_t stream) {
    const float* x     = (const float*)d_in[0];
    const int*   ei    = (const int*)d_in[1];
    const float* Wl    = (const float*)d_in[2];
    const float* bl    = (const float*)d_in[3];
    const float* Wr    = (const float*)d_in[4];
    const float* br    = (const float*)d_in[5];
    const float* gamma = (const float*)d_in[6];
    const float* beta  = (const float*)d_in[7];
    int N = in_sizes[0] / D;
    int E = in_sizes[1] / 2;
    int NB = (N + BROWS - 1) / BROWS;    // 782 (must be <= 1024)
    int eblocks = (E + 8191) / 8192;     // 98 (must be <= 128)

    float* ws = (float*)d_ws;
    float* bn_sum = ws;                                   // D
    float* bn_ss  = ws + D;                               // D
    unsigned short* xbf  = (unsigned short*)(ws + 4 * D); // N*D
    unsigned short* hbf  = xbf + (size_t)N * D;           // N*D
    unsigned short* Wcat = hbf + (size_t)N * D;           // 2*D*D
    int* gcur   = (int*)(Wcat + 2 * D * D);               // pad 1024
    int* bstart = gcur + 1024;                            // pad 1028
    int* ghT    = bstart + 1028;                          // 1024*128
    unsigned int* binned = (unsigned int*)(ghT + 1024 * 128); // E
    float* out = (float*)d_out;

    const int* rowi = ei;
    const int* coli = ei + E;

    setup_k<<<2048, 256, 0, stream>>>(x, Wl, Wr, rowi, xbf, Wcat, ghT, bn_sum,
                                      N, NB, E, eblocks);
    scanB_k<<<1, 1024, 0, stream>>>(ghT, bstart, gcur, NB, E, eblocks);
    binB_k<<<eblocks, 256, 0, stream>>>(rowi, coli, gcur, binned, E, NB);
    aggemm_k<<<NB * 2, 256, 0, stream>>>(xbf, binned, bstart, Wcat, bl, br,
                                         hbf, bn_sum, bn_ss, N);
    int total8 = N * D / 8;
    bnapply_k<<<(total8 + 255) / 256, 256, 0, stream>>>(hbf, out, bn_sum, bn_ss,
                                                        gamma, beta, total8,
                                                        1.0f / (float)N);
}

// Round 11
// 124.147 us; speedup vs baseline: 6.0499x; 1.0904x over previous
//
#include <hip/hip_runtime.h>
#include <hip/hip_bf16.h>

#define D 128
#define BSH 6                 // bucket = row >> 6 (64 rows/bucket)
#define BROWS 64
#define CH 4096               // edges per chunk (fast path: whole bucket <= CH)
#define AP 136                // padded bf16 row for A tiles (272B stride)

typedef __attribute__((ext_vector_type(8))) short bf16x8;
typedef __attribute__((ext_vector_type(8))) unsigned short ushort8;
typedef __attribute__((ext_vector_type(4))) float f32x4;

static __device__ __forceinline__ unsigned short f2bf(float f) {
    unsigned int u = __builtin_bit_cast(unsigned int, f);
    unsigned int r = (u + 0x7FFFu + ((u >> 16) & 1u)) >> 16;
    return (unsigned short)r;
}
static __device__ __forceinline__ float bf2f(unsigned short u) {
    return __builtin_bit_cast(float, ((unsigned int)u) << 16);
}
static __device__ __forceinline__ float bflo(unsigned int u) {
    return __builtin_bit_cast(float, u << 16);
}
static __device__ __forceinline__ float bfhi(unsigned int u) {
    return __builtin_bit_cast(float, u & 0xFFFF0000u);
}

// ---- setup: x->bf16, Wcat, zero BN acc, per-block bucket histograms -------
__global__ __launch_bounds__(256) void setup_k(const float* __restrict__ x,
                                               const float* __restrict__ Wl,
                                               const float* __restrict__ Wr,
                                               const int* __restrict__ rowi,
                                               unsigned short* __restrict__ xbf,
                                               unsigned short* __restrict__ Wcat,
                                               int* __restrict__ ghT,
                                               float* __restrict__ bn_acc,
                                               int N, int NB, int E, int eblocks) {
    __shared__ int hist[1024];
    int t = threadIdx.x;
    int gid = blockIdx.x * 256 + t;
    int stride = gridDim.x * 256;
    int total4 = N * D / 4;
    for (int i = gid; i < total4; i += stride) {
        float4 v = reinterpret_cast<const float4*>(x)[i];
        ushort4 o;
        o.x = f2bf(v.x); o.y = f2bf(v.y); o.z = f2bf(v.z); o.w = f2bf(v.w);
        reinterpret_cast<ushort4*>(xbf)[i] = o;
    }
    for (int i = gid; i < D * 2 * D; i += stride) {
        int o = i >> 8, k = i & 255;
        float v = (k < D) ? Wl[o * D + k] : Wr[o * D + (k - D)];
        Wcat[i] = f2bf(v);
    }
    if (gid < 2 * D) bn_acc[gid] = 0.f;

    if (blockIdx.x < (unsigned)eblocks) {
        for (int i = t; i < NB; i += 256) hist[i] = 0;
        __syncthreads();
        int base = blockIdx.x * 8192;
        #pragma unroll
        for (int k = 0; k < 32; ++k) {
            int e = base + k * 256 + t;
            if (e < E) atomicAdd(&hist[rowi[e] >> BSH], 1);
        }
        __syncthreads();
        for (int i = t; i < NB; i += 256) ghT[i * 128 + blockIdx.x] = hist[i];
    }
}

// ---- scanB: sum transposed slices + exclusive scan (NB <= 1024) -----------
__global__ __launch_bounds__(1024) void scanB_k(const int* __restrict__ ghT,
                                                int* __restrict__ bstart,
                                                int* __restrict__ gcur,
                                                int NB, int E, int eb) {
    __shared__ int lds[1024];
    int t = threadIdx.x;
    int v = 0;
    if (t < NB) {
        const int* row = ghT + (size_t)t * 128;
        int b = 0;
        for (; b + 4 <= eb; b += 4) {
            int4 q = *reinterpret_cast<const int4*>(row + b);
            v += q.x + q.y + q.z + q.w;
        }
        for (; b < eb; ++b) v += row[b];
    }
    lds[t] = v;
    __syncthreads();
    #pragma unroll
    for (int off = 1; off < 1024; off <<= 1) {
        int u = (t >= off) ? lds[t - off] : 0;
        __syncthreads();
        lds[t] += u;
        __syncthreads();
    }
    if (t < NB) {
        int s = lds[t] - v;
        bstart[t] = s;
        gcur[t] = s;
    }
    if (t == 0) bstart[NB] = E;
}

// ---- binB: scatter edges into bucket regions, packed (row<<16)|col --------
__global__ __launch_bounds__(256) void binB_k(const int* __restrict__ rowi,
                                              const int* __restrict__ coli,
                                              int* __restrict__ gcur,
                                              unsigned int* __restrict__ binned,
                                              int E, int NB) {
    __shared__ unsigned int stage[8192];
    __shared__ int hist[1024];
    __shared__ int basep[1024];
    __shared__ int cur[1024];
    int t = threadIdx.x;
    for (int i = t; i < NB; i += 256) { hist[i] = 0; cur[i] = 0; }
    __syncthreads();
    int base = blockIdx.x * 8192;
    int cnt = E - base; if (cnt > 8192) cnt = 8192;
    #pragma unroll
    for (int k = 0; k < 32; ++k) {
        int i = k * 256 + t;
        if (i < cnt) {
            int r = rowi[base + i], c = coli[base + i];
            stage[i] = ((unsigned int)r << 16) | (unsigned int)c;
            atomicAdd(&hist[r >> BSH], 1);
        }
    }
    __syncthreads();
    for (int i = t; i < NB; i += 256) {
        int h = hist[i];
        basep[i] = h ? atomicAdd(&gcur[i], h) : 0;
    }
    __syncthreads();
    #pragma unroll
    for (int k = 0; k < 32; ++k) {
        int i = k * 256 + t;
        if (i < cnt) {
            unsigned int p = stage[i];
            int b = p >> (16 + BSH);
            int pos = basep[b] + atomicAdd(&cur[b], 1);
            binned[pos] = p;
        }
    }
}

// ---- aggemm: bucket sort + 16-lane-group dwordx4 gather + MFMA + BN -------
// block b owns nodes [b*64, b*64+64); 512 thr = 8 waves
// fast path (bucket <= CH edges): 4 edges per load instr, 16B/lane
// gemm phase: wave w computes output cols [w*16, w*16+16) for all 64 rows
__global__ __launch_bounds__(512) void aggemm_k(const unsigned short* __restrict__ xbf,
                                                const unsigned int* __restrict__ binned,
                                                const int* __restrict__ bstart,
                                                const unsigned short* __restrict__ Wcat,
                                                const float* __restrict__ bl,
                                                const float* __restrict__ br,
                                                unsigned short* __restrict__ hbf,
                                                float* __restrict__ bn_sum,
                                                float* __restrict__ bn_ss, int N) {
    __shared__ __align__(16) unsigned short A_agg[BROWS][AP];    // 17408 B (dedicated)
    __shared__ __align__(16) unsigned char ubuf[BROWS * AP * 2]; // sorted / A_x union
    __shared__ int hist[BROWS];
    __shared__ int sincl[BROWS];
    __shared__ int sstart[BROWS + 1];
    __shared__ int scur[BROWS];
    __shared__ float bn_lds[2 * D];

    unsigned int* sorted = reinterpret_cast<unsigned int*>(ubuf);   // CH*4 = 16384 <= 17408
    unsigned short (*A_x)[AP] = reinterpret_cast<unsigned short (*)[AP]>(ubuf);

    int t = threadIdx.x;
    int b = blockIdx.x;
    int s = bstart[b], e = bstart[b + 1];
    int w = t >> 6, lane = t & 63;
    int lr = lane & 15, lk = lane >> 4;

    if (t < 2 * D) bn_lds[t] = 0.f;

    int total = e - s;
    if (total <= CH) {
        // ================= single-chunk FAST path =================
        int cnt = total;
        if (t < BROWS) hist[t] = 0;
        __syncthreads();
        #pragma unroll
        for (int k = 0; k < CH / 512; ++k) {
            int i = k * 512 + t;
            if (i < cnt) atomicAdd(&hist[(binned[s + i] >> 16) & (BROWS - 1)], 1);
        }
        __syncthreads();
        if (t < BROWS) sincl[t] = hist[t];
        __syncthreads();
        #pragma unroll
        for (int off = 1; off < BROWS; off <<= 1) {
            int u = 0;
            if (t < BROWS && t >= off) u = sincl[t - off];
            __syncthreads();
            if (t < BROWS) sincl[t] += u;
            __syncthreads();
        }
        if (t < BROWS) {
            int ex = sincl[t] - hist[t];
            sstart[t] = ex;
            scur[t] = ex;
        }
        if (t == 0) sstart[BROWS] = cnt;
        __syncthreads();
        #pragma unroll
        for (int k = 0; k < CH / 512; ++k) {
            int i = k * 512 + t;
            if (i < cnt) {
                unsigned int p = binned[s + i];
                int pos = atomicAdd(&scur[(p >> 16) & (BROWS - 1)], 1);
                sorted[pos] = p;
            }
        }
        __syncthreads();

        // gather: group g = lane>>4 handles edge j+g; lane loads 16B (8 cols)
        int g = lane >> 4, li = lane & 15;
        const unsigned short* xrow = xbf + li * 8;
        #pragma unroll
        for (int i = 0; i < 8; ++i) {
            int r = w * 8 + i;
            int js = sstart[r], je = sstart[r + 1];
            float a[8];
            #pragma unroll
            for (int k = 0; k < 8; ++k) a[k] = 0.f;
            int j = js;
            for (; j + 16 <= je; j += 16) {   // one full avg row per round
                uint4 v0 = *reinterpret_cast<const uint4*>(
                    xrow + (size_t)(sorted[j + g] & 0xFFFFu) * D);
                uint4 v1 = *reinterpret_cast<const uint4*>(
                    xrow + (size_t)(sorted[j + 4 + g] & 0xFFFFu) * D);
                uint4 v2 = *reinterpret_cast<const uint4*>(
                    xrow + (size_t)(sorted[j + 8 + g] & 0xFFFFu) * D);
                uint4 v3 = *reinterpret_cast<const uint4*>(
                    xrow + (size_t)(sorted[j + 12 + g] & 0xFFFFu) * D);
                a[0] += bflo(v0.x); a[1] += bfhi(v0.x);
                a[2] += bflo(v0.y); a[3] += bfhi(v0.y);
                a[4] += bflo(v0.z); a[5] += bfhi(v0.z);
                a[6] += bflo(v0.w); a[7] += bfhi(v0.w);
                a[0] += bflo(v1.x); a[1] += bfhi(v1.x);
                a[2] += bflo(v1.y); a[3] += bfhi(v1.y);
                a[4] += bflo(v1.z); a[5] += bfhi(v1.z);
                a[6] += bflo(v1.w); a[7] += bfhi(v1.w);
                a[0] += bflo(v2.x); a[1] += bfhi(v2.x);
                a[2] += bflo(v2.y); a[3] += bfhi(v2.y);
                a[4] += bflo(v2.z); a[5] += bfhi(v2.z);
                a[6] += bflo(v2.w); a[7] += bfhi(v2.w);
                a[0] += bflo(v3.x); a[1] += bfhi(v3.x);
                a[2] += bflo(v3.y); a[3] += bfhi(v3.y);
                a[4] += bflo(v3.z); a[5] += bfhi(v3.z);
                a[6] += bflo(v3.w); a[7] += bfhi(v3.w);
            }
            for (; j + 4 <= je; j += 4) {
                uint4 v = *reinterpret_cast<const uint4*>(
                    xrow + (size_t)(sorted[j + g] & 0xFFFFu) * D);
                a[0] += bflo(v.x); a[1] += bfhi(v.x);
                a[2] += bflo(v.y); a[3] += bfhi(v.y);
                a[4] += bflo(v.z); a[5] += bfhi(v.z);
                a[6] += bflo(v.w); a[7] += bfhi(v.w);
            }
            if (j < je) {                      // 1..3 leftover edges, masked
                int jj = j + g;
                float wgt = (jj < je) ? 1.f : 0.f;
                if (jj > je - 1) jj = je - 1;
                uint4 v = *reinterpret_cast<const uint4*>(
                    xrow + (size_t)(sorted[jj] & 0xFFFFu) * D);
                a[0] += wgt * bflo(v.x); a[1] += wgt * bfhi(v.x);
                a[2] += wgt * bflo(v.y); a[3] += wgt * bfhi(v.y);
                a[4] += wgt * bflo(v.z); a[5] += wgt * bfhi(v.z);
                a[6] += wgt * bflo(v.w); a[7] += wgt * bfhi(v.w);
            }
            // reduce the 4 groups (lanes xor 16, 32)
            #pragma unroll
            for (int k = 0; k < 8; ++k) {
                a[k] += __shfl_xor(a[k], 16);
                a[k] += __shfl_xor(a[k], 32);
            }
            if (g == 0) {
                unsigned int w0 = (unsigned int)f2bf(a[0]) | ((unsigned int)f2bf(a[1]) << 16);
                unsigned int w1 = (unsigned int)f2bf(a[2]) | ((unsigned int)f2bf(a[3]) << 16);
                unsigned int w2 = (unsigned int)f2bf(a[4]) | ((unsigned int)f2bf(a[5]) << 16);
                unsigned int w3 = (unsigned int)f2bf(a[6]) | ((unsigned int)f2bf(a[7]) << 16);
                *reinterpret_cast<uint4*>(&A_agg[r][li * 8]) = make_uint4(w0, w1, w2, w3);
            }
        }
    } else {
        // ================= multi-chunk SLOW path (R7) =================
        float a0[8], a1[8];
        #pragma unroll
        for (int i = 0; i < 8; ++i) { a0[i] = 0.f; a1[i] = 0.f; }
        const unsigned short* xb = xbf + lane * 2;

        for (int cs = s; cs < e; cs += CH) {
            int cnt = e - cs; if (cnt > CH) cnt = CH;
            if (t < BROWS) hist[t] = 0;
            __syncthreads();
            #pragma unroll
            for (int k = 0; k < CH / 512; ++k) {
                int i = k * 512 + t;
                if (i < cnt) atomicAdd(&hist[(binned[cs + i] >> 16) & (BROWS - 1)], 1);
            }
            __syncthreads();
            if (t < BROWS) sincl[t] = hist[t];
            __syncthreads();
            #pragma unroll
            for (int off = 1; off < BROWS; off <<= 1) {
                int u = 0;
                if (t < BROWS && t >= off) u = sincl[t - off];
                __syncthreads();
                if (t < BROWS) sincl[t] += u;
                __syncthreads();
            }
            if (t < BROWS) {
                int ex = sincl[t] - hist[t];
                sstart[t] = ex;
                scur[t] = ex;
            }
            if (t == 0) sstart[BROWS] = cnt;
            __syncthreads();
            #pragma unroll
            for (int k = 0; k < CH / 512; ++k) {
                int i = k * 512 + t;
                if (i < cnt) {
                    unsigned int p = binned[cs + i];
                    int pos = atomicAdd(&scur[(p >> 16) & (BROWS - 1)], 1);
                    sorted[pos] = p;
                }
            }
            __syncthreads();
            #pragma unroll
            for (int i = 0; i < 8; ++i) {
                int r = w * 8 + i;
                int js = sstart[r], je = sstart[r + 1];
                float s0 = a0[i], s1 = a1[i];
                int j = js;
                for (; j + 8 <= je; j += 8) {
                    unsigned int v[8];
                    #pragma unroll
                    for (int q = 0; q < 8; ++q)
                        v[q] = *reinterpret_cast<const unsigned int*>(
                            xb + (size_t)(sorted[j + q] & 0xFFFFu) * D);
                    #pragma unroll
                    for (int q = 0; q < 8; ++q) {
                        s0 += bf2f((unsigned short)v[q]);
                        s1 += bf2f((unsigned short)(v[q] >> 16));
                    }
                }
                for (; j < je; ++j) {
                    unsigned int v = *reinterpret_cast<const unsigned int*>(
                        xb + (size_t)(sorted[j] & 0xFFFFu) * D);
                    s0 += bf2f((unsigned short)v);
                    s1 += bf2f((unsigned short)(v >> 16));
                }
                a0[i] = s0; a1[i] = s1;
            }
            __syncthreads();
        }
        #pragma unroll
        for (int i = 0; i < 8; ++i) {
            int r = w * 8 + i;
            unsigned int o = (unsigned int)f2bf(a0[i]) | ((unsigned int)f2bf(a1[i]) << 16);
            *reinterpret_cast<unsigned int*>(&A_agg[r][lane * 2]) = o;
        }
    }
    __syncthreads();   // A_agg complete; sorted no longer needed

    // ---------- stage x -> A_x (overwrites sorted), hoist B ----------
    #pragma unroll
    for (int k = 0; k < 2; ++k) {
        int ch = k * 512 + t;          // 0..1023
        int r = ch >> 4;               // 0..63
        int c16 = ch & 15;             // 16B chunk
        int node = b * BROWS + r;
        ushort8 v = (ushort8){0, 0, 0, 0, 0, 0, 0, 0};
        if (node < N) v = *reinterpret_cast<const ushort8*>(&xbf[(size_t)node * D + c16 * 8]);
        *reinterpret_cast<ushort8*>(&A_x[r][c16 * 8]) = v;
    }
    bf16x8 Breg[8];
    #pragma unroll
    for (int ks = 0; ks < 8; ++ks)
        Breg[ks] = *reinterpret_cast<const bf16x8*>(
            &Wcat[(w * 16 + lr) * 256 + ks * 32 + lk * 8]);
    __syncthreads();

    // ---------- MFMA: K=256 (agg half + x half) ----------
    f32x4 acc[4];
    #pragma unroll
    for (int m = 0; m < 4; ++m) acc[m] = (f32x4){0.f, 0.f, 0.f, 0.f};
    #pragma unroll
    for (int m = 0; m < 4; ++m) {
        #pragma unroll
        for (int ks = 0; ks < 4; ++ks) {
            bf16x8 a = *reinterpret_cast<const bf16x8*>(&A_agg[m * 16 + lr][ks * 32 + lk * 8]);
            acc[m] = __builtin_amdgcn_mfma_f32_16x16x32_bf16(a, Breg[ks], acc[m], 0, 0, 0);
        }
        #pragma unroll
        for (int ks = 0; ks < 4; ++ks) {
            bf16x8 a = *reinterpret_cast<const bf16x8*>(&A_x[m * 16 + lr][ks * 32 + lk * 8]);
            acc[m] = __builtin_amdgcn_mfma_f32_16x16x32_bf16(a, Breg[ks + 4], acc[m], 0, 0, 0);
        }
    }

    // ---------- epilogue: bias + relu + store bf16 h + BN partials ----------
    int colo = w * 16 + lr;
    float bias = bl[colo] + br[colo];
    float s1 = 0.f, s2 = 0.f;
    #pragma unroll
    for (int m = 0; m < 4; ++m)
        #pragma unroll
        for (int ee = 0; ee < 4; ++ee) {
            int node = b * BROWS + m * 16 + lk * 4 + ee;
            if (node < N) {
                float hv = acc[m][ee] + bias;
                hv = hv > 0.f ? hv : 0.f;
                hbf[(size_t)node * D + colo] = f2bf(hv);
                s1 += hv;
                s2 += hv * hv;
            }
        }
    atomicAdd(&bn_lds[colo], s1);
    atomicAdd(&bn_lds[D + colo], s2);
    __syncthreads();
    if (t < D) {
        atomicAdd(&bn_sum[t], bn_lds[t]);
        atomicAdd(&bn_ss[t], bn_lds[D + t]);
    }
}

// ---- bnapply: out = h*scale + shift (finalize folded in) ------------------
__global__ __launch_bounds__(256) void bnapply_k(const unsigned short* __restrict__ hbf,
                                                 float* __restrict__ out,
                                                 const float* __restrict__ bn_sum,
                                                 const float* __restrict__ bn_ss,
                                                 const float* __restrict__ gamma,
                                                 const float* __restrict__ beta,
                                                 int total8, float invN) {
    int gid = blockIdx.x * 256 + threadIdx.x;
    if (gid >= total8) return;
    int d8 = (gid & 15) * 8;
    ushort8 hv = *reinterpret_cast<const ushort8*>(&hbf[(size_t)gid * 8]);
    float4 o0, o1;
    #pragma unroll
    for (int q = 0; q < 8; ++q) {
        int d = d8 + q;
        float m = bn_sum[d] * invN;
        float var = bn_ss[d] * invN - m * m;
        float r = rsqrtf(var + 1e-5f);
        float sc = gamma[d] * r;
        float sh = beta[d] - m * sc;
        float o = bf2f((unsigned short)hv[q]) * sc + sh;
        if (q < 4) { (&o0.x)[q] = o; } else { (&o1.x)[q - 4] = o; }
    }
    *reinterpret_cast<float4*>(out + (size_t)gid * 8) = o0;
    *reinterpret_cast<float4*>(out + (size_t)gid * 8 + 4) = o1;
}

extern "C" void kernel_launch(void* const* d_in, const int* in_sizes, int n_in,
                              void* d_out, int out_size, void* d_ws, size_t ws_size,
                              hipStream_t stream) {
    const float* x     = (const float*)d_in[0];
    const int*   ei    = (const int*)d_in[1];
    const float* Wl    = (const float*)d_in[2];
    const float* bl    = (const float*)d_in[3];
    const float* Wr    = (const float*)d_in[4];
    const float* br    = (const float*)d_in[5];
    const float* gamma = (const float*)d_in[6];
    const float* beta  = (const float*)d_in[7];
    int N = in_sizes[0] / D;
    int E = in_sizes[1] / 2;
    int NB = (N + BROWS - 1) / BROWS;    // 782 (must be <= 1024)
    int eblocks = (E + 8191) / 8192;     // 98 (must be <= 128)

    float* ws = (float*)d_ws;
    float* bn_sum = ws;                                   // D
    float* bn_ss  = ws + D;                               // D
    unsigned short* xbf  = (unsigned short*)(ws + 4 * D); // N*D
    unsigned short* hbf  = xbf + (size_t)N * D;           // N*D
    unsigned short* Wcat = hbf + (size_t)N * D;           // 2*D*D
    int* gcur   = (int*)(Wcat + 2 * D * D);               // pad 1024
    int* bstart = gcur + 1024;                            // pad 1028
    int* ghT    = bstart + 1028;                          // 1024*128
    unsigned int* binned = (unsigned int*)(ghT + 1024 * 128); // E
    float* out = (float*)d_out;

    const int* rowi = ei;
    const int* coli = ei + E;

    setup_k<<<2048, 256, 0, stream>>>(x, Wl, Wr, rowi, xbf, Wcat, ghT, bn_sum,
                                      N, NB, E, eblocks);
    scanB_k<<<1, 1024, 0, stream>>>(ghT, bstart, gcur, NB, E, eblocks);
    binB_k<<<eblocks, 256, 0, stream>>>(rowi, coli, gcur, binned, E, NB);
    aggemm_k<<<NB, 512, 0, stream>>>(xbf, binned, bstart, Wcat, bl, br,
                                     hbf, bn_sum, bn_ss, N);
    int total8 = N * D / 8;
    bnapply_k<<<(total8 + 255) / 256, 256, 0, stream>>>(hbf, out, bn_sum, bn_ss,
                                                        gamma, beta, total8,
                                                        1.0f / (float)N);
}

// Round 13
// 117.893 us; speedup vs baseline: 6.3709x; 1.0530x over previous
//
#include <hip/hip_runtime.h>
#include <hip/hip_bf16.h>

#define D 128
#define BSH 6                 // bucket = row >> 6 (64 rows/bucket)
#define BROWS 64
#define CH 4096               // edges per chunk in aggemm
#define AP 136                // padded bf16 row for A tiles (272B stride)
#define BEB 2048              // edges per binB block
#define QSCALE (127.0f / 6.0f)
#define IQSCALE (6.0f / 127.0f)

typedef __attribute__((ext_vector_type(8))) short bf16x8;
typedef __attribute__((ext_vector_type(8))) unsigned short ushort8;
typedef __attribute__((ext_vector_type(4))) float f32x4;

static __device__ __forceinline__ unsigned short f2bf(float f) {
    unsigned int u = __builtin_bit_cast(unsigned int, f);
    unsigned int r = (u + 0x7FFFu + ((u >> 16) & 1u)) >> 16;
    return (unsigned short)r;
}
static __device__ __forceinline__ float bf2f(unsigned short u) {
    return __builtin_bit_cast(float, ((unsigned int)u) << 16);
}
static __device__ __forceinline__ int q8(float f) {
    return (int)rintf(fminf(fmaxf(f, -6.f), 6.f) * QSCALE);
}

// ---- setup: x->int8 xq, Wcat bf16, zero BN acc, bucket histograms ---------
// ghT layout: [bucket][block-slot], slot stride 128 (eblocks <= 128)
__global__ __launch_bounds__(256) void setup_k(const float* __restrict__ x,
                                               const float* __restrict__ Wl,
                                               const float* __restrict__ Wr,
                                               const int* __restrict__ rowi,
                                               unsigned char* __restrict__ xq,
                                               unsigned short* __restrict__ Wcat,
                                               int* __restrict__ ghT,
                                               float* __restrict__ bn_acc,
                                               int N, int NB, int E, int eblocks) {
    __shared__ int hist[1024];
    int t = threadIdx.x;
    int gid = blockIdx.x * 256 + t;
    int stride = gridDim.x * 256;
    int total4 = N * D / 4;
    for (int i = gid; i < total4; i += stride) {
        float4 v = reinterpret_cast<const float4*>(x)[i];
        unsigned int p = (unsigned int)(q8(v.x) & 255)
                       | ((unsigned int)(q8(v.y) & 255) << 8)
                       | ((unsigned int)(q8(v.z) & 255) << 16)
                       | ((unsigned int)(q8(v.w) & 255) << 24);
        reinterpret_cast<unsigned int*>(xq)[i] = p;
    }
    for (int i = gid; i < D * 2 * D; i += stride) {
        int o = i >> 8, k = i & 255;
        float v = (k < D) ? Wl[o * D + k] : Wr[o * D + (k - D)];
        Wcat[i] = f2bf(v);
    }
    if (gid < 2 * D) bn_acc[gid] = 0.f;

    if (blockIdx.x < (unsigned)eblocks) {
        for (int i = t; i < NB; i += 256) hist[i] = 0;
        __syncthreads();
        int base = blockIdx.x * 8192;
        #pragma unroll
        for (int k = 0; k < 32; ++k) {
            int e = base + k * 256 + t;
            if (e < E) atomicAdd(&hist[rowi[e] >> BSH], 1);
        }
        __syncthreads();
        for (int i = t; i < NB; i += 256) ghT[i * 128 + blockIdx.x] = hist[i];
    }
}

// ---- scanB: sum transposed slices + exclusive scan (NB <= 1024) -----------
__global__ __launch_bounds__(1024) void scanB_k(const int* __restrict__ ghT,
                                                int* __restrict__ bstart,
                                                int* __restrict__ gcur,
                                                int NB, int E, int eb) {
    __shared__ int lds[1024];
    int t = threadIdx.x;
    int v = 0;
    if (t < NB) {
        const int* row = ghT + (size_t)t * 128;
        int b = 0;
        for (; b + 4 <= eb; b += 4) {
            int4 q = *reinterpret_cast<const int4*>(row + b);
            v += q.x + q.y + q.z + q.w;
        }
        for (; b < eb; ++b) v += row[b];
    }
    lds[t] = v;
    __syncthreads();
    #pragma unroll
    for (int off = 1; off < 1024; off <<= 1) {
        int u = (t >= off) ? lds[t - off] : 0;
        __syncthreads();
        lds[t] += u;
        __syncthreads();
    }
    if (t < NB) {
        int s = lds[t] - v;
        bstart[t] = s;
        gcur[t] = s;
    }
    if (t == 0) bstart[NB] = E;
}

// ---- binB: scatter edges into bucket regions, packed (row<<16)|col --------
__global__ __launch_bounds__(256) void binB_k(const int* __restrict__ rowi,
                                              const int* __restrict__ coli,
                                              int* __restrict__ gcur,
                                              unsigned int* __restrict__ binned,
                                              int E, int NB) {
    __shared__ unsigned int stage[BEB];
    __shared__ int hist[1024];
    __shared__ int basep[1024];
    __shared__ int cur[1024];
    int t = threadIdx.x;
    for (int i = t; i < NB; i += 256) { hist[i] = 0; cur[i] = 0; }
    __syncthreads();
    int base = blockIdx.x * BEB;
    int cnt = E - base; if (cnt > BEB) cnt = BEB;
    #pragma unroll
    for (int k = 0; k < BEB / 256; ++k) {
        int i = k * 256 + t;
        if (i < cnt) {
            int r = rowi[base + i], c = coli[base + i];
            stage[i] = ((unsigned int)r << 16) | (unsigned int)c;
            atomicAdd(&hist[r >> BSH], 1);
        }
    }
    __syncthreads();
    for (int i = t; i < NB; i += 256) {
        int h = hist[i];
        basep[i] = h ? atomicAdd(&gcur[i], h) : 0;
    }
    __syncthreads();
    #pragma unroll
    for (int k = 0; k < BEB / 256; ++k) {
        int i = k * 256 + t;
        if (i < cnt) {
            unsigned int p = stage[i];
            int b = p >> (16 + BSH);
            int pos = basep[b] + atomicAdd(&cur[b], 1);
            binned[pos] = p;
        }
    }
}

// ---- aggemm: bucket sort + int8 gather (2B/lane) + MFMA GEMM + BN ---------
// block b owns nodes [b*64, b*64+64); 512 thr = 8 waves
// agg: wave w owns rows [w*8, w*8+8), lane owns 2 feature cols, unroll-8,
//      exact int32 accumulation, one float scale per row at the end
// gemm: wave w computes output cols [w*16, w*16+16) for all 64 rows
__global__ __launch_bounds__(512) void aggemm_k(const float* __restrict__ x,
                                                const unsigned char* __restrict__ xq,
                                                const unsigned int* __restrict__ binned,
                                                const int* __restrict__ bstart,
                                                const unsigned short* __restrict__ Wcat,
                                                const float* __restrict__ bl,
                                                const float* __restrict__ br,
                                                unsigned short* __restrict__ hbf,
                                                float* __restrict__ bn_sum,
                                                float* __restrict__ bn_ss, int N) {
    __shared__ unsigned short A_agg[BROWS][AP];                  // 17408 B (dedicated)
    __shared__ __align__(16) unsigned char ubuf[BROWS * AP * 2]; // sorted / A_x union
    __shared__ int hist[BROWS];
    __shared__ int sincl[BROWS];
    __shared__ int sstart[BROWS + 1];
    __shared__ int scur[BROWS];
    __shared__ float bn_lds[2 * D];

    unsigned int* sorted = reinterpret_cast<unsigned int*>(ubuf);   // CH*4 = 16384 <= 17408
    unsigned short (*A_x)[AP] = reinterpret_cast<unsigned short (*)[AP]>(ubuf);

    int t = threadIdx.x;
    int b = blockIdx.x;
    int s = bstart[b], e = bstart[b + 1];
    int w = t >> 6, lane = t & 63;
    int lr = lane & 15, lk = lane >> 4;

    if (t < 2 * D) bn_lds[t] = 0.f;

    // ---------- agg phase (per-chunk counting sort + register gather) ------
    int ia0[8], ia1[8];
    #pragma unroll
    for (int i = 0; i < 8; ++i) { ia0[i] = 0; ia1[i] = 0; }
    const unsigned char* xqb = xq + lane * 2;

    for (int cs = s; cs < e; cs += CH) {
        int cnt = e - cs; if (cnt > CH) cnt = CH;
        if (t < BROWS) hist[t] = 0;
        __syncthreads();
        #pragma unroll
        for (int k = 0; k < CH / 512; ++k) {
            int i = k * 512 + t;
            if (i < cnt) atomicAdd(&hist[(binned[cs + i] >> 16) & (BROWS - 1)], 1);
        }
        __syncthreads();
        if (t < BROWS) sincl[t] = hist[t];
        __syncthreads();
        #pragma unroll
        for (int off = 1; off < BROWS; off <<= 1) {
            int u = 0;
            if (t < BROWS && t >= off) u = sincl[t - off];
            __syncthreads();
            if (t < BROWS) sincl[t] += u;
            __syncthreads();
        }
        if (t < BROWS) {
            int ex = sincl[t] - hist[t];
            sstart[t] = ex;
            scur[t] = ex;
        }
        if (t == 0) sstart[BROWS] = cnt;
        __syncthreads();
        #pragma unroll
        for (int k = 0; k < CH / 512; ++k) {
            int i = k * 512 + t;
            if (i < cnt) {
                unsigned int p = binned[cs + i];
                int pos = atomicAdd(&scur[(p >> 16) & (BROWS - 1)], 1);
                sorted[pos] = p;
            }
        }
        __syncthreads();
        // gather: wave w owns rows [w*8, w*8+8), unroll-8, int8 decode
        #pragma unroll
        for (int i = 0; i < 8; ++i) {
            int r = w * 8 + i;
            int js = sstart[r], je = sstart[r + 1];
            int s0 = ia0[i], s1 = ia1[i];
            int j = js;
            for (; j + 8 <= je; j += 8) {
                unsigned short v[8];
                #pragma unroll
                for (int q = 0; q < 8; ++q)
                    v[q] = *reinterpret_cast<const unsigned short*>(
                        xqb + (size_t)(sorted[j + q] & 0xFFFFu) * D);
                #pragma unroll
                for (int q = 0; q < 8; ++q) {
                    s0 += (int)(signed char)(v[q] & 0xFF);
                    s1 += (int)(signed char)(v[q] >> 8);
                }
            }
            if (j + 4 <= je) {
                unsigned short v[4];
                #pragma unroll
                for (int q = 0; q < 4; ++q)
                    v[q] = *reinterpret_cast<const unsigned short*>(
                        xqb + (size_t)(sorted[j + q] & 0xFFFFu) * D);
                #pragma unroll
                for (int q = 0; q < 4; ++q) {
                    s0 += (int)(signed char)(v[q] & 0xFF);
                    s1 += (int)(signed char)(v[q] >> 8);
                }
                j += 4;
            }
            for (; j < je; ++j) {
                unsigned short v = *reinterpret_cast<const unsigned short*>(
                    xqb + (size_t)(sorted[j] & 0xFFFFu) * D);
                s0 += (int)(signed char)(v & 0xFF);
                s1 += (int)(signed char)(v >> 8);
            }
            ia0[i] = s0; ia1[i] = s1;
        }
        __syncthreads();   // all waves done reading sorted for this chunk
    }

    // ---------- write agg -> A_agg, hoist B, stage x (f32) -> A_x ----------
    #pragma unroll
    for (int i = 0; i < 8; ++i) {
        int r = w * 8 + i;
        float a0 = (float)ia0[i] * IQSCALE;
        float a1 = (float)ia1[i] * IQSCALE;
        unsigned int o = (unsigned int)f2bf(a0) | ((unsigned int)f2bf(a1) << 16);
        *reinterpret_cast<unsigned int*>(&A_agg[r][lane * 2]) = o;
    }
    // B fragments: wave w cols [w*16, w*16+16), k = ks*32 + lk*8
    bf16x8 Breg[8];
    #pragma unroll
    for (int ks = 0; ks < 8; ++ks)
        Breg[ks] = *reinterpret_cast<const bf16x8*>(
            &Wcat[(w * 16 + lr) * 256 + ks * 32 + lk * 8]);
    // x rows -> A_x (overwrites sorted; safe: all waves passed the barrier)
    {
        int r = t >> 3;                // 0..63
        int c0 = (t & 7) * 16;         // 16 cols per thread
        int node = b * BROWS + r;
        unsigned int wb[8];
        if (node < N) {
            const float4* src = reinterpret_cast<const float4*>(x + (size_t)node * D + c0);
            #pragma unroll
            for (int q = 0; q < 4; ++q) {
                float4 f = src[q];
                wb[q * 2]     = (unsigned int)f2bf(f.x) | ((unsigned int)f2bf(f.y) << 16);
                wb[q * 2 + 1] = (unsigned int)f2bf(f.z) | ((unsigned int)f2bf(f.w) << 16);
            }
        } else {
            #pragma unroll
            for (int q = 0; q < 8; ++q) wb[q] = 0u;
        }
        *reinterpret_cast<uint4*>(&A_x[r][c0])     = make_uint4(wb[0], wb[1], wb[2], wb[3]);
        *reinterpret_cast<uint4*>(&A_x[r][c0 + 8]) = make_uint4(wb[4], wb[5], wb[6], wb[7]);
    }
    __syncthreads();

    // ---------- MFMA: K=256 (agg half + x half) ----------
    f32x4 acc[4];
    #pragma unroll
    for (int m = 0; m < 4; ++m) acc[m] = (f32x4){0.f, 0.f, 0.f, 0.f};
    #pragma unroll
    for (int m = 0; m < 4; ++m) {
        #pragma unroll
        for (int ks = 0; ks < 4; ++ks) {
            bf16x8 a = *reinterpret_cast<const bf16x8*>(&A_agg[m * 16 + lr][ks * 32 + lk * 8]);
            acc[m] = __builtin_amdgcn_mfma_f32_16x16x32_bf16(a, Breg[ks], acc[m], 0, 0, 0);
        }
        #pragma unroll
        for (int ks = 0; ks < 4; ++ks) {
            bf16x8 a = *reinterpret_cast<const bf16x8*>(&A_x[m * 16 + lr][ks * 32 + lk * 8]);
            acc[m] = __builtin_amdgcn_mfma_f32_16x16x32_bf16(a, Breg[ks + 4], acc[m], 0, 0, 0);
        }
    }

    // ---------- epilogue: bias + relu + store bf16 h + BN partials ----------
    int colo = w * 16 + lr;
    float bias = bl[colo] + br[colo];
    float s1 = 0.f, s2 = 0.f;
    #pragma unroll
    for (int m = 0; m < 4; ++m)
        #pragma unroll
        for (int ee = 0; ee < 4; ++ee) {
            int node = b * BROWS + m * 16 + lk * 4 + ee;
            if (node < N) {
                float hv = acc[m][ee] + bias;
                hv = hv > 0.f ? hv : 0.f;
                hbf[(size_t)node * D + colo] = f2bf(hv);
                s1 += hv;
                s2 += hv * hv;
            }
        }
    atomicAdd(&bn_lds[colo], s1);
    atomicAdd(&bn_lds[D + colo], s2);
    __syncthreads();
    if (t < D) {
        atomicAdd(&bn_sum[t], bn_lds[t]);
        atomicAdd(&bn_ss[t], bn_lds[D + t]);
    }
}

// ---- bnapply: finalize in LDS once per block, then out = h*sc + sh --------
__global__ __launch_bounds__(256) void bnapply_k(const unsigned short* __restrict__ hbf,
                                                 float* __restrict__ out,
                                                 const float* __restrict__ bn_sum,
                                                 const float* __restrict__ bn_ss,
                                                 const float* __restrict__ gamma,
                                                 const float* __restrict__ beta,
                                                 int total8, float invN) {
    __shared__ float sc_l[D], sh_l[D];
    int t = threadIdx.x;
    if (t < D) {
        float m = bn_sum[t] * invN;
        float var = bn_ss[t] * invN - m * m;
        float r = rsqrtf(var + 1e-5f);
        float sc = gamma[t] * r;
        sc_l[t] = sc;
        sh_l[t] = beta[t] - m * sc;
    }
    __syncthreads();
    int gid = blockIdx.x * 256 + t;
    if (gid >= total8) return;
    int d8 = (gid & 15) * 8;
    ushort8 hv = *reinterpret_cast<const ushort8*>(&hbf[(size_t)gid * 8]);
    float4 o0, o1;
    #pragma unroll
    for (int q = 0; q < 8; ++q) {
        float o = bf2f((unsigned short)hv[q]) * sc_l[d8 + q] + sh_l[d8 + q];
        if (q < 4) { (&o0.x)[q] = o; } else { (&o1.x)[q - 4] = o; }
    }
    *reinterpret_cast<float4*>(out + (size_t)gid * 8) = o0;
    *reinterpret_cast<float4*>(out + (size_t)gid * 8 + 4) = o1;
}

extern "C" void kernel_launch(void* const* d_in, const int* in_sizes, int n_in,
                              void* d_out, int out_size, void* d_ws, size_t ws_size,
                              hipStream_t stream) {
    const float* x     = (const float*)d_in[0];
    const int*   ei    = (const int*)d_in[1];
    const float* Wl    = (const float*)d_in[2];
    const float* bl    = (const float*)d_in[3];
    const float* Wr    = (const float*)d_in[4];
    const float* br    = (const float*)d_in[5];
    const float* gamma = (const float*)d_in[6];
    const float* beta  = (const float*)d_in[7];
    int N = in_sizes[0] / D;
    int E = in_sizes[1] / 2;
    int NB = (N + BROWS - 1) / BROWS;    // 782 (must be <= 1024)
    int eblocks = (E + 8191) / 8192;     // 98 (must be <= 128)

    float* ws = (float*)d_ws;
    float* bn_sum = ws;                                   // D
    float* bn_ss  = ws + D;                               // D
    unsigned short* hbf  = (unsigned short*)(ws + 4 * D); // N*D
    unsigned short* Wcat = hbf + (size_t)N * D;           // 2*D*D
    int* gcur   = (int*)(Wcat + 2 * D * D);               // pad 1024
    int* bstart = gcur + 1024;                            // pad 1028
    int* ghT    = bstart + 1028;                          // 1024*128
    unsigned int* binned = (unsigned int*)(ghT + 1024 * 128); // E
    unsigned char* xq = (unsigned char*)(binned + E);     // N*D bytes
    float* out = (float*)d_out;

    const int* rowi = ei;
    const int* coli = ei + E;

    setup_k<<<2048, 256, 0, stream>>>(x, Wl, Wr, rowi, xq, Wcat, ghT, bn_sum,
                                      N, NB, E, eblocks);
    scanB_k<<<1, 1024, 0, stream>>>(ghT, bstart, gcur, NB, E, eblocks);
    binB_k<<<(E + BEB - 1) / BEB, 256, 0, stream>>>(rowi, coli, gcur, binned, E, NB);
    aggemm_k<<<NB, 512, 0, stream>>>(x, xq, binned, bstart, Wcat, bl, br,
                                     hbf, bn_sum, bn_ss, N);
    int total8 = N * D / 8;
    bnapply_k<<<(total8 + 255) / 256, 256, 0, stream>>>(hbf, out, bn_sum, bn_ss,
                                                        gamma, beta, total8,
                                                        1.0f / (float)N);
}

// Round 14
// 116.429 us; speedup vs baseline: 6.4510x; 1.0126x over previous
//
#include <hip/hip_runtime.h>
#include <hip/hip_bf16.h>

#define D 128
#define BSH 6                 // bucket = row >> 6 (64 rows/bucket)
#define BROWS 64
#define CH 4096               // edges per chunk in aggemm
#define AP 136                // padded bf16 row for A tiles (272B stride)
#define BEB 2048              // edges per binB block

typedef __attribute__((ext_vector_type(8))) short bf16x8;
typedef __attribute__((ext_vector_type(8))) unsigned short ushort8;
typedef __attribute__((ext_vector_type(4))) float f32x4;

static __device__ __forceinline__ unsigned short f2bf(float f) {
    unsigned int u = __builtin_bit_cast(unsigned int, f);
    unsigned int r = (u + 0x7FFFu + ((u >> 16) & 1u)) >> 16;
    return (unsigned short)r;
}
static __device__ __forceinline__ float bf2f(unsigned short u) {
    return __builtin_bit_cast(float, ((unsigned int)u) << 16);
}

// ---- setup: x->bf16, Wcat, zero BN acc, per-block bucket histograms -------
// ghT layout: [bucket][block-slot], slot stride 128 (eblocks <= 128)
__global__ __launch_bounds__(256) void setup_k(const float* __restrict__ x,
                                               const float* __restrict__ Wl,
                                               const float* __restrict__ Wr,
                                               const int* __restrict__ rowi,
                                               unsigned short* __restrict__ xbf,
                                               unsigned short* __restrict__ Wcat,
                                               int* __restrict__ ghT,
                                               float* __restrict__ bn_acc,
                                               int N, int NB, int E, int eblocks) {
    __shared__ int hist[1024];
    int t = threadIdx.x;
    int gid = blockIdx.x * 256 + t;
    int stride = gridDim.x * 256;
    int total4 = N * D / 4;
    for (int i = gid; i < total4; i += stride) {
        float4 v = reinterpret_cast<const float4*>(x)[i];
        ushort4 o;
        o.x = f2bf(v.x); o.y = f2bf(v.y); o.z = f2bf(v.z); o.w = f2bf(v.w);
        reinterpret_cast<ushort4*>(xbf)[i] = o;
    }
    for (int i = gid; i < D * 2 * D; i += stride) {
        int o = i >> 8, k = i & 255;
        float v = (k < D) ? Wl[o * D + k] : Wr[o * D + (k - D)];
        Wcat[i] = f2bf(v);
    }
    if (gid < 2 * D) bn_acc[gid] = 0.f;

    if (blockIdx.x < (unsigned)eblocks) {
        for (int i = t; i < NB; i += 256) hist[i] = 0;
        __syncthreads();
        int base = blockIdx.x * 8192;
        #pragma unroll
        for (int k = 0; k < 32; ++k) {
            int e = base + k * 256 + t;
            if (e < E) atomicAdd(&hist[rowi[e] >> BSH], 1);
        }
        __syncthreads();
        for (int i = t; i < NB; i += 256) ghT[i * 128 + blockIdx.x] = hist[i];
    }
}

// ---- scanB: sum transposed slices + exclusive scan (NB <= 1024) -----------
__global__ __launch_bounds__(1024) void scanB_k(const int* __restrict__ ghT,
                                                int* __restrict__ bstart,
                                                int* __restrict__ gcur,
                                                int NB, int E, int eb) {
    __shared__ int lds[1024];
    int t = threadIdx.x;
    int v = 0;
    if (t < NB) {
        const int* row = ghT + (size_t)t * 128;
        int b = 0;
        for (; b + 4 <= eb; b += 4) {
            int4 q = *reinterpret_cast<const int4*>(row + b);
            v += q.x + q.y + q.z + q.w;
        }
        for (; b < eb; ++b) v += row[b];
    }
    lds[t] = v;
    __syncthreads();
    #pragma unroll
    for (int off = 1; off < 1024; off <<= 1) {
        int u = (t >= off) ? lds[t - off] : 0;
        __syncthreads();
        lds[t] += u;
        __syncthreads();
    }
    if (t < NB) {
        int s = lds[t] - v;
        bstart[t] = s;
        gcur[t] = s;
    }
    if (t == 0) bstart[NB] = E;
}

// ---- binB: scatter edges into bucket regions, packed (row<<16)|col --------
__global__ __launch_bounds__(256) void binB_k(const int* __restrict__ rowi,
                                              const int* __restrict__ coli,
                                              int* __restrict__ gcur,
                                              unsigned int* __restrict__ binned,
                                              int E, int NB) {
    __shared__ unsigned int stage[BEB];
    __shared__ int hist[1024];
    __shared__ int basep[1024];
    __shared__ int cur[1024];
    int t = threadIdx.x;
    for (int i = t; i < NB; i += 256) { hist[i] = 0; cur[i] = 0; }
    __syncthreads();
    int base = blockIdx.x * BEB;
    int cnt = E - base; if (cnt > BEB) cnt = BEB;
    #pragma unroll
    for (int k = 0; k < BEB / 256; ++k) {
        int i = k * 256 + t;
        if (i < cnt) {
            int r = rowi[base + i], c = coli[base + i];
            stage[i] = ((unsigned int)r << 16) | (unsigned int)c;
            atomicAdd(&hist[r >> BSH], 1);
        }
    }
    __syncthreads();
    for (int i = t; i < NB; i += 256) {
        int h = hist[i];
        basep[i] = h ? atomicAdd(&gcur[i], h) : 0;
    }
    __syncthreads();
    #pragma unroll
    for (int k = 0; k < BEB / 256; ++k) {
        int i = k * 256 + t;
        if (i < cnt) {
            unsigned int p = stage[i];
            int b = p >> (16 + BSH);
            int pos = basep[b] + atomicAdd(&cur[b], 1);
            binned[pos] = p;
        }
    }
}

// ---- aggemm (R7-proven): bucket sort + bf16 register gather + MFMA + BN ---
// block b owns nodes [b*64, b*64+64); 512 thr = 8 waves
// x rows staged into dedicated A_x at START (latency hidden under sort+agg);
// agg result written into the sorted-union buffer at the end.
__global__ __launch_bounds__(512) void aggemm_k(const unsigned short* __restrict__ xbf,
                                                const unsigned int* __restrict__ binned,
                                                const int* __restrict__ bstart,
                                                const unsigned short* __restrict__ Wcat,
                                                const float* __restrict__ bl,
                                                const float* __restrict__ br,
                                                unsigned short* __restrict__ hbf,
                                                float* __restrict__ bn_sum,
                                                float* __restrict__ bn_ss, int N) {
    __shared__ unsigned short A_x[BROWS][AP];                    // 17408 B (dedicated)
    __shared__ __align__(16) unsigned char ubuf[BROWS * AP * 2]; // sorted / A_agg union
    __shared__ int hist[BROWS];
    __shared__ int sincl[BROWS];
    __shared__ int sstart[BROWS + 1];
    __shared__ int scur[BROWS];
    __shared__ float bn_lds[2 * D];

    unsigned int* sorted = reinterpret_cast<unsigned int*>(ubuf);   // CH*4 = 16384 <= 17408
    unsigned short (*A_agg)[AP] = reinterpret_cast<unsigned short (*)[AP]>(ubuf);

    int t = threadIdx.x;
    int b = blockIdx.x;
    int s = bstart[b], e = bstart[b + 1];
    int w = t >> 6, lane = t & 63;
    int lr = lane & 15, lk = lane >> 4;

    if (t < 2 * D) bn_lds[t] = 0.f;

    // stage own-row x -> A_x NOW; loads retire while we sort/aggregate
    #pragma unroll
    for (int k = 0; k < 2; ++k) {
        int ch = k * 512 + t;          // 0..1023
        int r = ch >> 4;               // 0..63
        int c16 = ch & 15;             // 16B chunk
        int node = b * BROWS + r;
        ushort8 v = (ushort8){0, 0, 0, 0, 0, 0, 0, 0};
        if (node < N) v = *reinterpret_cast<const ushort8*>(&xbf[(size_t)node * D + c16 * 8]);
        *reinterpret_cast<ushort8*>(&A_x[r][c16 * 8]) = v;
    }

    // ---------- agg phase ----------
    float a0[8], a1[8];
    #pragma unroll
    for (int i = 0; i < 8; ++i) { a0[i] = 0.f; a1[i] = 0.f; }
    const unsigned short* xb = xbf + lane * 2;

    for (int cs = s; cs < e; cs += CH) {
        int cnt = e - cs; if (cnt > CH) cnt = CH;
        if (t < BROWS) hist[t] = 0;
        __syncthreads();
        #pragma unroll
        for (int k = 0; k < CH / 512; ++k) {
            int i = k * 512 + t;
            if (i < cnt) atomicAdd(&hist[(binned[cs + i] >> 16) & (BROWS - 1)], 1);
        }
        __syncthreads();
        if (t < BROWS) sincl[t] = hist[t];
        __syncthreads();
        #pragma unroll
        for (int off = 1; off < BROWS; off <<= 1) {
            int u = 0;
            if (t < BROWS && t >= off) u = sincl[t - off];
            __syncthreads();
            if (t < BROWS) sincl[t] += u;
            __syncthreads();
        }
        if (t < BROWS) {
            int ex = sincl[t] - hist[t];
            sstart[t] = ex;
            scur[t] = ex;
        }
        if (t == 0) sstart[BROWS] = cnt;
        __syncthreads();
        #pragma unroll
        for (int k = 0; k < CH / 512; ++k) {
            int i = k * 512 + t;
            if (i < cnt) {
                unsigned int p = binned[cs + i];
                int pos = atomicAdd(&scur[(p >> 16) & (BROWS - 1)], 1);
                sorted[pos] = p;
            }
        }
        __syncthreads();
        // gather: wave w owns rows [w*8, w*8+8), unroll-8
        #pragma unroll
        for (int i = 0; i < 8; ++i) {
            int r = w * 8 + i;
            int js = sstart[r], je = sstart[r + 1];
            float s0 = a0[i], s1 = a1[i];
            int j = js;
            for (; j + 8 <= je; j += 8) {
                unsigned int v[8];
                #pragma unroll
                for (int q = 0; q < 8; ++q)
                    v[q] = *reinterpret_cast<const unsigned int*>(
                        xb + (size_t)(sorted[j + q] & 0xFFFFu) * D);
                #pragma unroll
                for (int q = 0; q < 8; ++q) {
                    s0 += bf2f((unsigned short)v[q]);
                    s1 += bf2f((unsigned short)(v[q] >> 16));
                }
            }
            if (j + 4 <= je) {
                unsigned int v[4];
                #pragma unroll
                for (int q = 0; q < 4; ++q)
                    v[q] = *reinterpret_cast<const unsigned int*>(
                        xb + (size_t)(sorted[j + q] & 0xFFFFu) * D);
                #pragma unroll
                for (int q = 0; q < 4; ++q) {
                    s0 += bf2f((unsigned short)v[q]);
                    s1 += bf2f((unsigned short)(v[q] >> 16));
                }
                j += 4;
            }
            for (; j < je; ++j) {
                unsigned int v = *reinterpret_cast<const unsigned int*>(
                    xb + (size_t)(sorted[j] & 0xFFFFu) * D);
                s0 += bf2f((unsigned short)v);
                s1 += bf2f((unsigned short)(v >> 16));
            }
            a0[i] = s0; a1[i] = s1;
        }
        __syncthreads();   // all waves done reading sorted for this chunk
    }

    // ---------- write agg -> A_agg (union buf), hoist B ----------
    #pragma unroll
    for (int i = 0; i < 8; ++i) {
        int r = w * 8 + i;
        unsigned int o = (unsigned int)f2bf(a0[i]) | ((unsigned int)f2bf(a1[i]) << 16);
        *reinterpret_cast<unsigned int*>(&A_agg[r][lane * 2]) = o;
    }
    bf16x8 Breg[8];
    #pragma unroll
    for (int ks = 0; ks < 8; ++ks)
        Breg[ks] = *reinterpret_cast<const bf16x8*>(
            &Wcat[(w * 16 + lr) * 256 + ks * 32 + lk * 8]);
    __syncthreads();

    // ---------- MFMA: K=256 (agg half + x half) ----------
    f32x4 acc[4];
    #pragma unroll
    for (int m = 0; m < 4; ++m) acc[m] = (f32x4){0.f, 0.f, 0.f, 0.f};
    #pragma unroll
    for (int m = 0; m < 4; ++m) {
        #pragma unroll
        for (int ks = 0; ks < 4; ++ks) {
            bf16x8 a = *reinterpret_cast<const bf16x8*>(&A_agg[m * 16 + lr][ks * 32 + lk * 8]);
            acc[m] = __builtin_amdgcn_mfma_f32_16x16x32_bf16(a, Breg[ks], acc[m], 0, 0, 0);
        }
        #pragma unroll
        for (int ks = 0; ks < 4; ++ks) {
            bf16x8 a = *reinterpret_cast<const bf16x8*>(&A_x[m * 16 + lr][ks * 32 + lk * 8]);
            acc[m] = __builtin_amdgcn_mfma_f32_16x16x32_bf16(a, Breg[ks + 4], acc[m], 0, 0, 0);
        }
    }

    // ---------- epilogue: bias + relu + store bf16 h + BN partials ----------
    int colo = w * 16 + lr;
    float bias = bl[colo] + br[colo];
    float s1 = 0.f, s2 = 0.f;
    #pragma unroll
    for (int m = 0; m < 4; ++m)
        #pragma unroll
        for (int ee = 0; ee < 4; ++ee) {
            int node = b * BROWS + m * 16 + lk * 4 + ee;
            if (node < N) {
                float hv = acc[m][ee] + bias;
                hv = hv > 0.f ? hv : 0.f;
                hbf[(size_t)node * D + colo] = f2bf(hv);
                s1 += hv;
                s2 += hv * hv;
            }
        }
    atomicAdd(&bn_lds[colo], s1);
    atomicAdd(&bn_lds[D + colo], s2);
    __syncthreads();
    if (t < D) {
        atomicAdd(&bn_sum[t], bn_lds[t]);
        atomicAdd(&bn_ss[t], bn_lds[D + t]);
    }
}

// ---- bnapply: finalize in LDS once per block, then out = h*sc + sh --------
__global__ __launch_bounds__(256) void bnapply_k(const unsigned short* __restrict__ hbf,
                                                 float* __restrict__ out,
                                                 const float* __restrict__ bn_sum,
                                                 const float* __restrict__ bn_ss,
                                                 const float* __restrict__ gamma,
                                                 const float* __restrict__ beta,
                                                 int total8, float invN) {
    __shared__ float sc_l[D], sh_l[D];
    int t = threadIdx.x;
    if (t < D) {
        float m = bn_sum[t] * invN;
        float var = bn_ss[t] * invN - m * m;
        float r = rsqrtf(var + 1e-5f);
        float sc = gamma[t] * r;
        sc_l[t] = sc;
        sh_l[t] = beta[t] - m * sc;
    }
    __syncthreads();
    int gid = blockIdx.x * 256 + t;
    if (gid >= total8) return;
    int d8 = (gid & 15) * 8;
    ushort8 hv = *reinterpret_cast<const ushort8*>(&hbf[(size_t)gid * 8]);
    float4 o0, o1;
    #pragma unroll
    for (int q = 0; q < 8; ++q) {
        float o = bf2f((unsigned short)hv[q]) * sc_l[d8 + q] + sh_l[d8 + q];
        if (q < 4) { (&o0.x)[q] = o; } else { (&o1.x)[q - 4] = o; }
    }
    *reinterpret_cast<float4*>(out + (size_t)gid * 8) = o0;
    *reinterpret_cast<float4*>(out + (size_t)gid * 8 + 4) = o1;
}

extern "C" void kernel_launch(void* const* d_in, const int* in_sizes, int n_in,
                              void* d_out, int out_size, void* d_ws, size_t ws_size,
                              hipStream_t stream) {
    const float* x     = (const float*)d_in[0];
    const int*   ei    = (const int*)d_in[1];
    const float* Wl    = (const float*)d_in[2];
    const float* bl    = (const float*)d_in[3];
    const float* Wr    = (const float*)d_in[4];
    const float* br    = (const float*)d_in[5];
    const float* gamma = (const float*)d_in[6];
    const float* beta  = (const float*)d_in[7];
    int N = in_sizes[0] / D;
    int E = in_sizes[1] / 2;
    int NB = (N + BROWS - 1) / BROWS;    // 782 (must be <= 1024)
    int eblocks = (E + 8191) / 8192;     // 98 (must be <= 128)

    float* ws = (float*)d_ws;
    float* bn_sum = ws;                                   // D
    float* bn_ss  = ws + D;                               // D
    unsigned short* xbf  = (unsigned short*)(ws + 4 * D); // N*D
    unsigned short* hbf  = xbf + (size_t)N * D;           // N*D
    unsigned short* Wcat = hbf + (size_t)N * D;           // 2*D*D
    int* gcur   = (int*)(Wcat + 2 * D * D);               // pad 1024
    int* bstart = gcur + 1024;                            // pad 1028
    int* ghT    = bstart + 1028;                          // 1024*128
    unsigned int* binned = (unsigned int*)(ghT + 1024 * 128); // E
    float* out = (float*)d_out;

    const int* rowi = ei;
    const int* coli = ei + E;

    setup_k<<<2048, 256, 0, stream>>>(x, Wl, Wr, rowi, xbf, Wcat, ghT, bn_sum,
                                      N, NB, E, eblocks);
    scanB_k<<<1, 1024, 0, stream>>>(ghT, bstart, gcur, NB, E, eblocks);
    binB_k<<<(E + BEB - 1) / BEB, 256, 0, stream>>>(rowi, coli, gcur, binned, E, NB);
    aggemm_k<<<NB, 512, 0, stream>>>(xbf, binned, bstart, Wcat, bl, br,
                                     hbf, bn_sum, bn_ss, N);
    int total8 = N * D / 8;
    bnapply_k<<<(total8 + 255) / 256, 256, 0, stream>>>(hbf, out, bn_sum, bn_ss,
                                                        gamma, beta, total8,
                                                        1.0f / (float)N);
}